// Round 1
// baseline (281.799 us; speedup 1.0000x reference)
//
#include <hip/hip_runtime.h>

// Problem constants (fixed by the reference):
//   B=32, C=256, H=64, W=64.  Positions = B*H*W = 131072.
//   Pure streaming reduction: 268 MB read once -> floor ~43 us @ 6.3 TB/s.
//
// v2 theory: previous kernel (279.7 us, ~0.96 TB/s) was LATENCY-bound:
//   scalar dword loads (256 B/wave-instr) x 8 waves/CU gave only ~2-8 KB
//   in flight per CU vs the ~9.2 KB needed (10.25 B/cy x ~900 cy).
// Fix: float4 loads along hw (1 KiB/wave-instr) + split the 256-channel
//   loop across 8 waves (block=512) with an LDS combine -> 16 waves/CU,
//   ~8 KB in flight per wave.

#define BB   32
#define CC   256
#define HH   64
#define WW   64
#define HWSZ (HH * WW)            // 4096 floats per (b,c) plane
#define NPOS (BB * HWSZ)          // 131072 positions
#define HW4  (HWSZ / 4)           // 1024 float4 per plane
#define PPB  256                  // positions per block
#define NW   8                    // waves per block (512 threads)
#define CPW  (CC / NW)            // 32 channels per wave
#define SIM_EPS 1e-8f

__global__ __launch_bounds__(512) void
sim_reduce_kernel(const float4* __restrict__ u4,
                  const float4* __restrict__ m4,
                  const int*    __restrict__ mask,
                  double*       __restrict__ ws)
{
    // Per-wave channel-chunk partials for the block's 256 positions.
    // Written as float4 (conflict-free ds_write_b128, contiguous per wave),
    // read back scalar stride-1 (conflict-free).
    __shared__ float4 s_num[NW][64];
    __shared__ float4 s_uu [NW][64];
    __shared__ float4 s_mm [NW][64];

    const int wv = threadIdx.x >> 6;     // wave id: which 32-channel chunk
    const int l  = threadIdx.x & 63;     // lane: which float4 group of positions

    const int pos0 = blockIdx.x * PPB;   // block's first position
    const int b    = pos0 >> 12;         // pos0 / 4096 (PPB divides HWSZ -> single b)
    const int hw0  = pos0 & (HWSZ - 1);

    // float4 index of this thread's 4 positions at its first channel.
    const size_t base4 = (size_t)b * CC * HW4
                       + (size_t)(wv * CPW) * HW4
                       + (size_t)(hw0 >> 2) + (size_t)l;
    const float4* __restrict__ up = u4 + base4;
    const float4* __restrict__ mp = m4 + base4;

    float4 num = make_float4(0.f, 0.f, 0.f, 0.f);
    float4 uu  = make_float4(0.f, 0.f, 0.f, 0.f);
    float4 mm  = make_float4(0.f, 0.f, 0.f, 0.f);

#pragma unroll 4
    for (int c = 0; c < CPW; ++c) {
        const float4 a  = up[(size_t)c * HW4];
        const float4 bv = mp[(size_t)c * HW4];
        num.x = fmaf(a.x, bv.x, num.x);
        num.y = fmaf(a.y, bv.y, num.y);
        num.z = fmaf(a.z, bv.z, num.z);
        num.w = fmaf(a.w, bv.w, num.w);
        uu.x  = fmaf(a.x, a.x,  uu.x);
        uu.y  = fmaf(a.y, a.y,  uu.y);
        uu.z  = fmaf(a.z, a.z,  uu.z);
        uu.w  = fmaf(a.w, a.w,  uu.w);
        mm.x  = fmaf(bv.x, bv.x, mm.x);
        mm.y  = fmaf(bv.y, bv.y, mm.y);
        mm.z  = fmaf(bv.z, bv.z, mm.z);
        mm.w  = fmaf(bv.w, bv.w, mm.w);
    }

    s_num[wv][l] = num;
    s_uu [wv][l] = uu;
    s_mm [wv][l] = mm;
    __syncthreads();

    // Phase 2: first 4 waves combine the 8 channel-chunk partials per position,
    // compute cosine sim, apply mask.
    double sd = 0.0, md = 0.0;
    if (threadIdx.x < PPB) {
        const int t = threadIdx.x;
        float fn = 0.f, fu = 0.f, fm = 0.f;
#pragma unroll
        for (int k = 0; k < NW; ++k) {
            fn += ((const float*)s_num[k])[t];
            fu += ((const float*)s_uu [k])[t];
            fm += ((const float*)s_mm [k])[t];
        }
        const float denom = fmaxf(sqrtf(fu), SIM_EPS) * fmaxf(sqrtf(fm), SIM_EPS);
        const float sim   = fn / denom;
        if (mask[pos0 + t] != 0) { sd = (double)sim; md = 1.0; }
    }

    // Block reduction: wave shfl (inactive waves contribute 0) -> LDS -> atomic.
#pragma unroll
    for (int off = 32; off > 0; off >>= 1) {
        sd += __shfl_down(sd, off, 64);
        md += __shfl_down(md, off, 64);
    }

    __shared__ double r_s[NW];
    __shared__ double r_m[NW];
    if (l == 0) { r_s[wv] = sd; r_m[wv] = md; }
    __syncthreads();

    if (threadIdx.x == 0) {
        double ts = 0.0, tm = 0.0;
#pragma unroll
        for (int k = 0; k < NW; ++k) { ts += r_s[k]; tm += r_m[k]; }
        atomicAdd(&ws[0], ts);   // device-scope by default on CDNA
        atomicAdd(&ws[1], tm);
    }
}

__global__ void finalize_kernel(const double* __restrict__ ws,
                                float* __restrict__ out)
{
    out[0] = (float)(ws[0] / ws[1]);
}

extern "C" void kernel_launch(void* const* d_in, const int* in_sizes, int n_in,
                              void* d_out, int out_size, void* d_ws, size_t ws_size,
                              hipStream_t stream)
{
    const float4* u4   = (const float4*)d_in[0];
    const float4* m4   = (const float4*)d_in[1];
    const int*    mask = (const int*)d_in[2];
    float*  out = (float*)d_out;
    double* ws  = (double*)d_ws;

    // ws is re-poisoned before every timed launch -> zero it on-stream
    // (async memset is graph-capture safe).
    hipMemsetAsync(d_ws, 0, 2 * sizeof(double), stream);

    sim_reduce_kernel<<<NPOS / PPB, 512, 0, stream>>>(u4, m4, mask, ws);
    finalize_kernel<<<1, 1, 0, stream>>>(ws, out);
}